// Round 1
// 498.866 us; speedup vs baseline: 1.0889x; 1.0889x over previous
//
#include <hip/hip_runtime.h>
#include <math.h>

#define Cc     8
#define FIELD  7
#define PAD    3
#define TILE   16
#define HALO   22        // TILE + 2*PAD
#define BB     32
#define HH     384
#define WW     384
#define NSLOT  56        // 8 dy' x 7 dx slots for a row-PAIR
#define NG     14        // 56/4 K-groups; slot sigma = 14*g + S  (no padding!)
#define UCLIP  13.815510557964274f   // -log(1e-6)

typedef __attribute__((ext_vector_type(8))) short short8;  // 8 bf16 = 4 VGPRs
typedef __attribute__((ext_vector_type(4))) float f32x4;   // MFMA C/D

__device__ __forceinline__ unsigned short f2bf(float f) {   // RNE fp32->bf16
    unsigned u = __float_as_uint(f);
    u += 0x7FFFu + ((u >> 16) & 1u);
    return (unsigned short)(u >> 16);
}

// ---------------------------------------------------------------------------
// prep_w: row-pair fused weight table.
// Slot s = dy'*7 + dx, dy' in [0,8), dx in [0,7). For n = 8h + d (h = row
// half, d = out channel): wtab[s][n][j] = W[(dy'-h)*7 + dx][j][d] if
// 0 <= dy'-h < 7 else 0, where W[tap][j][d] = sum_c kw[tap][j][c]*(c!=j)*sw[c][d]
// (7x7 conv fused with the 1x1 k_scale matmul, off-diagonal mask on (cin,cout)).
// Layout: B-fragment lane (n = lane&15, g = lane>>4) reads 8 contiguous j.
// ---------------------------------------------------------------------------
__global__ __launch_bounds__(256)
void prep_w(const float* __restrict__ kw, const float* __restrict__ sw,
            unsigned short* __restrict__ wtab) {
    int it = blockIdx.x * 256 + threadIdx.x;      // (slot, j=cin)
    if (it >= NSLOT * 8) return;
    int s = it >> 3, j = it & 7;
    int dyp = s / 7, dx = s - dyp * 7;
#pragma unroll
    for (int n = 0; n < 16; ++n) {
        int h = n >> 3, d = n & 7;
        int dy = dyp - h;
        float a = 0.f;
        if (dy >= 0 && dy < FIELD) {
            int tap = dy * 7 + dx;
#pragma unroll
            for (int c = 0; c < Cc; ++c) {
                float kv = (c == j) ? 0.f : kw[(tap * Cc + j) * Cc + c];
                a = fmaf(kv, sw[c * Cc + d], a);
            }
        }
        wtab[(s * 16 + n) * 8 + j] = f2bf(a);
    }
}

// ---------------------------------------------------------------------------
// init_qv: q0 = softmax(x) packed bf16x8; v = b - u@W  (u = min(lse-x, UCLIP))
// ---------------------------------------------------------------------------
__global__ __launch_bounds__(256)
void init_qv(const float* __restrict__ x, const float* __restrict__ sw,
             const float* __restrict__ sb,
             uint4* __restrict__ q0, float* __restrict__ v) {
    long long p = (long long)blockIdx.x * 256 + threadIdx.x;
    const float4* xp = (const float4*)(x + p * Cc);
    float4 a0 = xp[0], a1 = xp[1];
    float xv[Cc] = {a0.x, a0.y, a0.z, a0.w, a1.x, a1.y, a1.z, a1.w};
    float m = xv[0];
#pragma unroll
    for (int c = 1; c < Cc; ++c) m = fmaxf(m, xv[c]);
    float s = 0.f, e[Cc];
#pragma unroll
    for (int c = 0; c < Cc; ++c) { e[c] = __expf(xv[c] - m); s += e[c]; }
    float inv = 1.f / s;
    uint4 qo;
    qo.x = f2bf(e[0] * inv) | ((unsigned)f2bf(e[1] * inv) << 16);
    qo.y = f2bf(e[2] * inv) | ((unsigned)f2bf(e[3] * inv) << 16);
    qo.z = f2bf(e[4] * inv) | ((unsigned)f2bf(e[5] * inv) << 16);
    qo.w = f2bf(e[6] * inv) | ((unsigned)f2bf(e[7] * inv) << 16);
    q0[p] = qo;

    float lse = m + __logf(s);
    float u[Cc];
#pragma unroll
    for (int c = 0; c < Cc; ++c) u[c] = fminf(lse - xv[c], UCLIP);
    float vv[Cc];
#pragma unroll
    for (int d = 0; d < Cc; ++d) {
        float a = sb[d];
#pragma unroll
        for (int c = 0; c < Cc; ++c) a = fmaf(-u[c], sw[c * Cc + d], a);
        vv[d] = a;
    }
    float4* vp = (float4*)(v + p * Cc);
    vp[0] = make_float4(vv[0], vv[1], vv[2], vv[3]);
    vp[1] = make_float4(vv[4], vv[5], vv[6], vv[7]);
}

// ---------------------------------------------------------------------------
// mrf_iter: logits = v - conv7x7(q, k'); out = softmax(logits) bf16 (or
// logits fp32 on the last iteration).
// Conv via mfma_f32_16x16x32_bf16 with ROW-PAIR N-packing:
//   M = 16 pixels (one tile row), N = 16 = 2 output rows x 8 channels,
//   K = 32 = 4 slots x 8 cin.  Each A-fragment read (input row rp+dy') feeds
//   BOTH output rows of a pair -> half the LDS reads + half the MFMAs of the
//   per-row scheme. Slot sigma = 14*g + S makes dy' = 2g + (S>=7), dx = S%7
//   (no in-loop integer division).
// Block = 256 threads = 4 waves; wave w owns row pairs (4w,4w+1),(4w+2,4w+3).
// ---------------------------------------------------------------------------
__global__ __launch_bounds__(256)
void mrf_iter(const uint4* __restrict__ qin,          // bf16x8 per pixel
              const unsigned short* __restrict__ wtab,
              const float* __restrict__ v,            // fp32, 8 per pixel
              uint4* __restrict__ qout,               // next q (bf16) if !last
              float* __restrict__ lout,               // logits fp32 if last
              int last) {
    __shared__ __align__(16) uint4 qs[HALO * HALO];     // 7744 B, bf16x8/pixel
    __shared__ __align__(16) float pen[TILE * TILE * Cc]; // 8192 B

    const int tid = threadIdx.x;
    const int wv  = tid >> 6;        // wave 0..3
    const int l   = tid & 63;
    const int m   = l & 15;          // A-row = px;  also B/D-col = n
    const int g   = l >> 4;          // K-group

    const int w0 = blockIdx.x * TILE;
    const int h0 = blockIdx.y * TILE;
    const int b  = blockIdx.z;

    // --- B fragments: 14 x (8 bf16) from the precomputed table (L1/L2-hot) ---
    short8 bw[NG];
#pragma unroll
    for (int S = 0; S < NG; ++S) {
        uint4 t = *(const uint4*)(wtab + ((g * NG + S) * 16 + m) * 8);
        bw[S] = __builtin_bit_cast(short8, t);
    }

    // --- stage q tile + halo (bf16x8 per pixel, zero-pad = SAME) ---
    const uint4* qb = qin + (long long)b * HH * WW;
    for (int s = tid; s < HALO * HALO; s += 256) {
        int sy = s / HALO, sx = s - sy * HALO;
        int gh = h0 + sy - PAD, gw = w0 + sx - PAD;
        uint4 val = make_uint4(0, 0, 0, 0);
        if (gh >= 0 && gh < HH && gw >= 0 && gw < WW)
            val = qb[(long long)gh * WW + gw];
        qs[s] = val;
    }
    __syncthreads();

    // --- K loop: 14 groups x 2 pairs; dy' = 2g + (S>=7), dx = S%7 ---
    f32x4 acc0 = (f32x4){0.f, 0.f, 0.f, 0.f};
    f32x4 acc1 = (f32x4){0.f, 0.f, 0.f, 0.f};
    const int r0   = 4 * wv;                 // pair0 top row; pair1 = r0+2
    const int base = (2 * g) * HALO + m;
#pragma unroll
    for (int S = 0; S < NG; ++S) {
        const int off = base + ((S >= 7) ? HALO : 0) + (S % 7);
        short8 a0 = *(const short8*)&qs[off + r0 * HALO];
        acc0 = __builtin_amdgcn_mfma_f32_16x16x32_bf16(a0, bw[S], acc0, 0, 0, 0);
        short8 a1 = *(const short8*)&qs[off + (r0 + 2) * HALO];
        acc1 = __builtin_amdgcn_mfma_f32_16x16x32_bf16(a1, bw[S], acc1, 0, 0, 0);
    }

    // --- scatter D: lane holds D[px=g*4+t][n=m]; n = 8*h + d -> row r0+2p+h ---
    {
        const int hb = m >> 3, d = m & 7;
#pragma unroll
        for (int t = 0; t < 4; ++t) {
            int px = g * 4 + t;
            pen[((r0 + hb) * TILE + px) * Cc + d]     = acc0[t];
            pen[((r0 + 2 + hb) * TILE + px) * Cc + d] = acc1[t];
        }
    }
    __syncthreads();

    // --- epilogue: one thread per pixel ---
    const int px = tid & 15, py = tid >> 4;
    const long long pix = ((long long)b * HH + (h0 + py)) * WW + (w0 + px);
    const float4* pp = (const float4*)&pen[tid * Cc];
    float4 p0 = pp[0], p1 = pp[1];
    const float4* vp = (const float4*)(v + pix * Cc);
    float4 v0 = vp[0], v1 = vp[1];
    float o[Cc] = {v0.x - p0.x, v0.y - p0.y, v0.z - p0.z, v0.w - p0.w,
                   v1.x - p1.x, v1.y - p1.y, v1.z - p1.z, v1.w - p1.w};
    if (last) {
        float4* op = (float4*)(lout + pix * Cc);
        op[0] = make_float4(o[0], o[1], o[2], o[3]);
        op[1] = make_float4(o[4], o[5], o[6], o[7]);
    } else {
        float mm = o[0];
#pragma unroll
        for (int d = 1; d < Cc; ++d) mm = fmaxf(mm, o[d]);
        float ss = 0.f, e[Cc];
#pragma unroll
        for (int d = 0; d < Cc; ++d) { e[d] = __expf(o[d] - mm); ss += e[d]; }
        float inv = 1.f / ss;
        uint4 qo;
        qo.x = f2bf(e[0] * inv) | ((unsigned)f2bf(e[1] * inv) << 16);
        qo.y = f2bf(e[2] * inv) | ((unsigned)f2bf(e[3] * inv) << 16);
        qo.z = f2bf(e[4] * inv) | ((unsigned)f2bf(e[5] * inv) << 16);
        qo.w = f2bf(e[6] * inv) | ((unsigned)f2bf(e[7] * inv) << 16);
        qout[pix] = qo;
    }
}

extern "C" void kernel_launch(void* const* d_in, const int* in_sizes, int n_in,
                              void* d_out, int out_size, void* d_ws, size_t ws_size,
                              hipStream_t stream) {
    (void)in_sizes; (void)n_in; (void)out_size; (void)ws_size;
    const float* x  = (const float*)d_in[0];   // [32,384,384,8]
    const float* kw = (const float*)d_in[1];   // [7,7,8,8]
    const float* sw = (const float*)d_in[2];   // [8,8]
    const float* sb = (const float*)d_in[3];   // [8]

    const size_t QSZ = (size_t)BB * HH * WW * 16;        // 75,497,472 B (bf16x8)
    uint4* qA = (uint4*)d_ws;
    uint4* qB = (uint4*)((char*)d_ws + QSZ);
    unsigned short* wt = (unsigned short*)((char*)d_ws + 2 * QSZ);  // 14336 B
    float* vbuf = (float*)d_out;   // v lives in d_out; last iter overwrites in place

    prep_w<<<2, 256, 0, stream>>>(kw, sw, wt);

    const long long npix = (long long)BB * HH * WW;
    init_qv<<<(int)(npix / 256), 256, 0, stream>>>(x, sw, sb, qA, vbuf);

    dim3 grid(WW / TILE, HH / TILE, BB);   // 24 x 24 x 32
    mrf_iter<<<grid, 256, 0, stream>>>(qA, wt, vbuf, qB, nullptr, 0);
    mrf_iter<<<grid, 256, 0, stream>>>(qB, wt, vbuf, qA, nullptr, 0);
    mrf_iter<<<grid, 256, 0, stream>>>(qA, wt, vbuf, qB, nullptr, 0);
    mrf_iter<<<grid, 256, 0, stream>>>(qB, wt, vbuf, qA, nullptr, 0);
    mrf_iter<<<grid, 256, 0, stream>>>(qA, wt, vbuf, nullptr, (float*)d_out, 1);
}

// Round 2
// 496.158 us; speedup vs baseline: 1.0948x; 1.0055x over previous
//
#include <hip/hip_runtime.h>
#include <math.h>

#define Cc     8
#define FIELD  7
#define PAD    3
#define TILE   16
#define HALO   22        // TILE + 2*PAD
#define QSTR   23        // qs row stride (uint4): pad 22->23 so the 4 K-group
                         // row offsets (dRow=2) hit distinct bank sets {0,24,16,8}
#define PSTR   261       // pen channel-plane stride (dwords); 261%32=5 ->
                         // scatter banks (5d+4g+16hb+t) near-injective
#define BB     32
#define HH     384
#define WW     384
#define NSLOT  56        // 8 dy' x 7 dx slots for a row-PAIR
#define NG     14        // 56/4 K-groups; slot sigma = 14*g + S
#define UCLIP  13.815510557964274f   // -log(1e-6)

typedef __attribute__((ext_vector_type(8))) short short8;  // 8 bf16 = 4 VGPRs
typedef __attribute__((ext_vector_type(4))) float f32x4;   // MFMA C/D

__device__ __forceinline__ unsigned short f2bf(float f) {   // RNE fp32->bf16
    unsigned u = __float_as_uint(f);
    u += 0x7FFFu + ((u >> 16) & 1u);
    return (unsigned short)(u >> 16);
}

// ---------------------------------------------------------------------------
// prep_w: row-pair fused weight table.
// Slot s = dy'*7 + dx, dy' in [0,8), dx in [0,7). For n = 8h + d (h = row
// half, d = out channel): wtab[s][n][j] = W[(dy'-h)*7 + dx][j][d] if
// 0 <= dy'-h < 7 else 0, where W[tap][j][d] = sum_c kw[tap][j][c]*(c!=j)*sw[c][d]
// ---------------------------------------------------------------------------
__global__ __launch_bounds__(256)
void prep_w(const float* __restrict__ kw, const float* __restrict__ sw,
            unsigned short* __restrict__ wtab) {
    int it = blockIdx.x * 256 + threadIdx.x;      // (slot, j=cin)
    if (it >= NSLOT * 8) return;
    int s = it >> 3, j = it & 7;
    int dyp = s / 7, dx = s - dyp * 7;
#pragma unroll
    for (int n = 0; n < 16; ++n) {
        int h = n >> 3, d = n & 7;
        int dy = dyp - h;
        float a = 0.f;
        if (dy >= 0 && dy < FIELD) {
            int tap = dy * 7 + dx;
#pragma unroll
            for (int c = 0; c < Cc; ++c) {
                float kv = (c == j) ? 0.f : kw[(tap * Cc + j) * Cc + c];
                a = fmaf(kv, sw[c * Cc + d], a);
            }
        }
        wtab[(s * 16 + n) * 8 + j] = f2bf(a);
    }
}

// ---------------------------------------------------------------------------
// init_qv: q0 = softmax(x) packed bf16x8; v = b - u@W  (u = min(lse-x, UCLIP))
// ---------------------------------------------------------------------------
__global__ __launch_bounds__(256)
void init_qv(const float* __restrict__ x, const float* __restrict__ sw,
             const float* __restrict__ sb,
             uint4* __restrict__ q0, float* __restrict__ v) {
    long long p = (long long)blockIdx.x * 256 + threadIdx.x;
    const float4* xp = (const float4*)(x + p * Cc);
    float4 a0 = xp[0], a1 = xp[1];
    float xv[Cc] = {a0.x, a0.y, a0.z, a0.w, a1.x, a1.y, a1.z, a1.w};
    float m = xv[0];
#pragma unroll
    for (int c = 1; c < Cc; ++c) m = fmaxf(m, xv[c]);
    float s = 0.f, e[Cc];
#pragma unroll
    for (int c = 0; c < Cc; ++c) { e[c] = __expf(xv[c] - m); s += e[c]; }
    float inv = 1.f / s;
    uint4 qo;
    qo.x = f2bf(e[0] * inv) | ((unsigned)f2bf(e[1] * inv) << 16);
    qo.y = f2bf(e[2] * inv) | ((unsigned)f2bf(e[3] * inv) << 16);
    qo.z = f2bf(e[4] * inv) | ((unsigned)f2bf(e[5] * inv) << 16);
    qo.w = f2bf(e[6] * inv) | ((unsigned)f2bf(e[7] * inv) << 16);
    q0[p] = qo;

    float lse = m + __logf(s);
    float u[Cc];
#pragma unroll
    for (int c = 0; c < Cc; ++c) u[c] = fminf(lse - xv[c], UCLIP);
    float vv[Cc];
#pragma unroll
    for (int d = 0; d < Cc; ++d) {
        float a = sb[d];
#pragma unroll
        for (int c = 0; c < Cc; ++c) a = fmaf(-u[c], sw[c * Cc + d], a);
        vv[d] = a;
    }
    float4* vp = (float4*)(v + p * Cc);
    vp[0] = make_float4(vv[0], vv[1], vv[2], vv[3]);
    vp[1] = make_float4(vv[4], vv[5], vv[6], vv[7]);
}

// ---------------------------------------------------------------------------
// mrf_iter: logits = v - conv7x7(q, k'); out = softmax(logits) bf16 (or
// logits fp32 on the last iteration). Row-pair N-packed MFMA conv:
//   M=16 px, N=16 = 2 rows x 8 ch, K=32 = 4 slots x 8 cin.
// LDS layouts tuned for bank behavior:
//   qs row stride 23 (not 22): K-groups (dRow=2) -> bank offsets {0,24,16,8}.
//   pen channel-planar, plane stride 261: scatter ~conflict-free; epilogue
//   reads 8x b32 with consecutive lanes (2-way, free).
// ---------------------------------------------------------------------------
__global__ __launch_bounds__(256)
void mrf_iter(const uint4* __restrict__ qin,          // bf16x8 per pixel
              const unsigned short* __restrict__ wtab,
              const float* __restrict__ v,            // fp32, 8 per pixel
              uint4* __restrict__ qout,               // next q (bf16) if !last
              float* __restrict__ lout,               // logits fp32 if last
              int last) {
    __shared__ __align__(16) uint4 qs[HALO * QSTR];     // 506*16 = 8096 B
    __shared__ __align__(16) float pen[Cc * PSTR];      // 8352 B

    const int tid = threadIdx.x;
    const int wv  = tid >> 6;        // wave 0..3
    const int l   = tid & 63;
    const int m   = l & 15;          // A-row = px;  also B/D-col = n
    const int g   = l >> 4;          // K-group

    const int w0 = blockIdx.x * TILE;
    const int h0 = blockIdx.y * TILE;
    const int b  = blockIdx.z;

    // --- hoisted epilogue loads: v for this thread's pixel (latency hiding) ---
    const int px = tid & 15, py = tid >> 4;
    const long long pix = ((long long)b * HH + (h0 + py)) * WW + (w0 + px);
    const float4* vp = (const float4*)(v + pix * Cc);
    float4 v0 = vp[0], v1 = vp[1];

    // --- B fragments: 14 x (8 bf16) from the precomputed table (L2-hot) ---
    short8 bw[NG];
#pragma unroll
    for (int S = 0; S < NG; ++S) {
        uint4 t = *(const uint4*)(wtab + ((g * NG + S) * 16 + m) * 8);
        bw[S] = __builtin_bit_cast(short8, t);
    }

    // --- stage q tile + halo (bf16x8 per pixel, zero-pad = SAME) ---
    const uint4* qb = qin + (long long)b * HH * WW;
    for (int s = tid; s < HALO * HALO; s += 256) {
        int sy = s / HALO, sx = s - sy * HALO;
        int gh = h0 + sy - PAD, gw = w0 + sx - PAD;
        uint4 val = make_uint4(0, 0, 0, 0);
        if (gh >= 0 && gh < HH && gw >= 0 && gw < WW)
            val = qb[(long long)gh * WW + gw];
        qs[sy * QSTR + sx] = val;
    }
    __syncthreads();

    // --- K loop: 14 groups x 2 pairs; dy' = 2g + (S>=7), dx = S%7 ---
    f32x4 acc0 = (f32x4){0.f, 0.f, 0.f, 0.f};
    f32x4 acc1 = (f32x4){0.f, 0.f, 0.f, 0.f};
    const int r0   = 4 * wv;                 // pair0 top row; pair1 = r0+2
    const int base = (2 * g) * QSTR + m;
#pragma unroll
    for (int S = 0; S < NG; ++S) {
        const int off = base + ((S >= 7) ? QSTR : 0) + (S % 7);
        short8 a0 = *(const short8*)&qs[off + r0 * QSTR];
        acc0 = __builtin_amdgcn_mfma_f32_16x16x32_bf16(a0, bw[S], acc0, 0, 0, 0);
        short8 a1 = *(const short8*)&qs[off + (r0 + 2) * QSTR];
        acc1 = __builtin_amdgcn_mfma_f32_16x16x32_bf16(a1, bw[S], acc1, 0, 0, 0);
    }

    // --- scatter D to planar pen: lane holds D[px=4g+t][n=m], n=8hb+d ---
    {
        const int hb = m >> 3, d = m & 7;
        const int col = 4 * g;
#pragma unroll
        for (int t = 0; t < 4; ++t) {
            pen[d * PSTR + (r0 + hb) * TILE + col + t]     = acc0[t];
            pen[d * PSTR + (r0 + 2 + hb) * TILE + col + t] = acc1[t];
        }
    }
    __syncthreads();

    // --- epilogue: one thread per pixel (pix/v loaded up top) ---
    float o[Cc];
#pragma unroll
    for (int c = 0; c < Cc; ++c) o[c] = pen[c * PSTR + tid];
    o[0] = v0.x - o[0]; o[1] = v0.y - o[1]; o[2] = v0.z - o[2]; o[3] = v0.w - o[3];
    o[4] = v1.x - o[4]; o[5] = v1.y - o[5]; o[6] = v1.z - o[6]; o[7] = v1.w - o[7];
    if (last) {
        float4* op = (float4*)(lout + pix * Cc);
        op[0] = make_float4(o[0], o[1], o[2], o[3]);
        op[1] = make_float4(o[4], o[5], o[6], o[7]);
    } else {
        float mm = o[0];
#pragma unroll
        for (int d = 1; d < Cc; ++d) mm = fmaxf(mm, o[d]);
        float ss = 0.f, e[Cc];
#pragma unroll
        for (int d = 0; d < Cc; ++d) { e[d] = __expf(o[d] - mm); ss += e[d]; }
        float inv = 1.f / ss;
        uint4 qo;
        qo.x = f2bf(e[0] * inv) | ((unsigned)f2bf(e[1] * inv) << 16);
        qo.y = f2bf(e[2] * inv) | ((unsigned)f2bf(e[3] * inv) << 16);
        qo.z = f2bf(e[4] * inv) | ((unsigned)f2bf(e[5] * inv) << 16);
        qo.w = f2bf(e[6] * inv) | ((unsigned)f2bf(e[7] * inv) << 16);
        qout[pix] = qo;
    }
}

extern "C" void kernel_launch(void* const* d_in, const int* in_sizes, int n_in,
                              void* d_out, int out_size, void* d_ws, size_t ws_size,
                              hipStream_t stream) {
    (void)in_sizes; (void)n_in; (void)out_size; (void)ws_size;
    const float* x  = (const float*)d_in[0];   // [32,384,384,8]
    const float* kw = (const float*)d_in[1];   // [7,7,8,8]
    const float* sw = (const float*)d_in[2];   // [8,8]
    const float* sb = (const float*)d_in[3];   // [8]

    const size_t QSZ = (size_t)BB * HH * WW * 16;        // 75,497,472 B (bf16x8)
    uint4* qA = (uint4*)d_ws;
    uint4* qB = (uint4*)((char*)d_ws + QSZ);
    unsigned short* wt = (unsigned short*)((char*)d_ws + 2 * QSZ);  // 14336 B
    float* vbuf = (float*)d_out;   // v lives in d_out; last iter overwrites in place

    prep_w<<<2, 256, 0, stream>>>(kw, sw, wt);

    const long long npix = (long long)BB * HH * WW;
    init_qv<<<(int)(npix / 256), 256, 0, stream>>>(x, sw, sb, qA, vbuf);

    dim3 grid(WW / TILE, HH / TILE, BB);   // 24 x 24 x 32
    mrf_iter<<<grid, 256, 0, stream>>>(qA, wt, vbuf, qB, nullptr, 0);
    mrf_iter<<<grid, 256, 0, stream>>>(qB, wt, vbuf, qA, nullptr, 0);
    mrf_iter<<<grid, 256, 0, stream>>>(qA, wt, vbuf, qB, nullptr, 0);
    mrf_iter<<<grid, 256, 0, stream>>>(qB, wt, vbuf, qA, nullptr, 0);
    mrf_iter<<<grid, 256, 0, stream>>>(qA, wt, vbuf, nullptr, (float*)d_out, 1);
}